// Round 14
// baseline (298.456 us; speedup 1.0000x reference)
//
#include <hip/hip_runtime.h>

#define N_NODES 50000
#define N_PAD 50048          // 782 * 64
#define N_EDGES 800000
#define IN_F 96
#define OUT_F 128
#define KTOT 384             // GEMM K dim, k-major: K = k*96 + f

#define NB 782               // buckets of 64 rows: 782*64 = 50048 >= 50000
#define EPB 4096             // edges per block in bucket passes
#define NBLK ((N_EDGES + EPB - 1) / EPB)  // 196

#define SPMM_BLOCKS 4096     // persistent grid-stride SpMM

#define PSTR ((size_t)N_PAD * 32)   // shorts per feature plane (32 feats)
#define PQ ((size_t)N_PAD * 8)      // uint2 per feature plane

typedef __attribute__((ext_vector_type(8))) short bf16x8;
typedef __attribute__((ext_vector_type(4))) float f32x4;

__device__ __forceinline__ short f2bf(float x) {
  union { float f; unsigned u; } c;
  c.f = x;
  unsigned u = c.u;
  u = (u + 0x7FFFu + ((u >> 16) & 1u)) >> 16;  // round-to-nearest-even
  return (short)u;
}

__device__ __forceinline__ float bflo(unsigned u) {
  union { unsigned u; float f; } c;
  c.u = u << 16;
  return c.f;
}
__device__ __forceinline__ float bfhi(unsigned u) {
  union { unsigned u; float f; } c;
  c.u = u & 0xffff0000u;
  return c.f;
}

// ---------------- CSR build: bucketed 2-pass + per-bucket row sort ----------

__global__ __launch_bounds__(256) void passA_kernel(const int* __restrict__ rows,
                                                    int* __restrict__ hist) {
  __shared__ int h[NB];
  int B = blockIdx.x;
  for (int b = threadIdx.x; b < NB; b += 256) h[b] = 0;
  __syncthreads();
  int end = min((B + 1) * EPB, N_EDGES);
  for (int i = B * EPB + threadIdx.x; i < end; i += 256) atomicAdd(&h[rows[i] >> 6], 1);
  __syncthreads();
  for (int b = threadIdx.x; b < NB; b += 256) hist[b * NBLK + B] = h[b];
}

__global__ __launch_bounds__(256) void scanA_kernel(const int* __restrict__ hist,
                                                    int* __restrict__ off,
                                                    int* __restrict__ total) {
  __shared__ int tmp[256];
  int b = blockIdx.x;
  int tid = threadIdx.x;
  int v = (tid < NBLK) ? hist[b * NBLK + tid] : 0;
  tmp[tid] = v;
  __syncthreads();
  for (int o = 1; o < 256; o <<= 1) {
    int t = (tid >= o) ? tmp[tid - o] : 0;
    __syncthreads();
    tmp[tid] += t;
    __syncthreads();
  }
  if (tid < NBLK) off[b * NBLK + tid] = tmp[tid] - v;
  if (tid == 255) total[b] = tmp[tid];
}

__global__ __launch_bounds__(1024) void scanB_kernel(const int* __restrict__ total,
                                                     int* __restrict__ bucket_start) {
  __shared__ int tmp[1024];
  int tid = threadIdx.x;
  int v = (tid < NB) ? total[tid] : 0;
  tmp[tid] = v;
  __syncthreads();
  for (int o = 1; o < 1024; o <<= 1) {
    int t = (tid >= o) ? tmp[tid - o] : 0;
    __syncthreads();
    tmp[tid] += t;
    __syncthreads();
  }
  if (tid < NB) bucket_start[tid] = tmp[tid] - v;
  if (tid == 0) bucket_start[NB] = N_EDGES;
}

// rec.x = col (16b, N<65536) | local_row (6b) << 16 ; rec.y = fp32 val bits
__global__ __launch_bounds__(256) void passB_kernel(
    const int* __restrict__ rows, const int* __restrict__ cols,
    const float* __restrict__ vals, const int* __restrict__ off,
    const int* __restrict__ bucket_start, int2* __restrict__ recs) {
  __shared__ int cur[NB];
  int B = blockIdx.x;
  for (int b = threadIdx.x; b < NB; b += 256)
    cur[b] = bucket_start[b] + off[b * NBLK + B];
  __syncthreads();
  int end = min((B + 1) * EPB, N_EDGES);
  for (int i = B * EPB + threadIdx.x; i < end; i += 256) {
    int r = rows[i];
    int pos = atomicAdd(&cur[r >> 6], 1);
    recs[pos] = make_int2((cols[i] & 0xffff) | ((r & 63) << 16), __float_as_int(vals[i]));
  }
}

__global__ __launch_bounds__(256) void bsort_kernel(
    const int* __restrict__ bucket_start, const int2* __restrict__ recs,
    int2* __restrict__ recs2, int* __restrict__ row_start) {
  __shared__ int hist[64], excl[64], cur[64];
  int b = blockIdx.x;
  int tid = threadIdx.x;
  if (tid < 64) hist[tid] = 0;
  __syncthreads();
  int s = bucket_start[b], e = bucket_start[b + 1];
  for (int i = s + tid; i < e; i += 256) atomicAdd(&hist[(recs[i].x >> 16) & 63], 1);
  __syncthreads();
  if (tid == 0) {
    int acc = 0;
    for (int j = 0; j < 64; ++j) {
      excl[j] = acc;
      acc += hist[j];
    }
  }
  __syncthreads();
  if (tid < 64) {
    cur[tid] = excl[tid];
    int r = b * 64 + tid;
    if (r < N_NODES) row_start[r] = s + excl[tid];
  }
  if (b == 0 && tid == 0) row_start[N_NODES] = N_EDGES;
  __syncthreads();
  for (int i = s + tid; i < e; i += 256) {
    int2 rec = recs[i];
    int lr = (rec.x >> 16) & 63;
    int pos = s + atomicAdd(&cur[lr], 1);
    recs2[pos] = make_int2(rec.x & 0xffff, rec.y);
  }
}

// ---------------- dtype prep (fused x + W), slice-major x ----------------
// xb = 3 planes of [N_PAD][32 feats] bf16; plane p holds feats p*32..p*32+31.

#define NXD (N_NODES * 48)  // dword-pairs of x (2 feats each)

__global__ void convert_xw_kernel(const float* __restrict__ x, unsigned* __restrict__ xb,
                                  const float* __restrict__ W, short* __restrict__ Wb) {
  int i = blockIdx.x * blockDim.x + threadIdx.x;
  if (i < NXD) {
    float2 v = reinterpret_cast<const float2*>(x)[i];
    int n = i / 48;
    int d = i - n * 48;      // dword within row, feats 2d,2d+1
    int p = d >> 4;          // plane
    int pd = d & 15;         // dword within plane row
    xb[p * (N_PAD * 16) + n * 16 + pd] =
        (unsigned)(unsigned short)f2bf(v.x) | ((unsigned)(unsigned short)f2bf(v.y) << 16);
  } else if (i < NXD + OUT_F * KTOT) {
    int j = i - NXD;
    int o = j / KTOT;
    int r = j - o * KTOT;
    int k = r / IN_F;
    int f = r - k * IN_F;
    Wb[j] = f2bf(W[o * KTOT + f * 4 + k]);  // k-major K axis
  }
}

// ---------------- SpMM on one 32-feat slice --------------------------------
// y_s[row,:] = alpha * sum_e val[e]*v_s[col[e],:] + beta * prev_s[row,:]
// gather set = one plane (3.2 MB) -> L2-resident per XCD.
// 64 lanes = 8 edge-slots x 8 lanes; lane loads 1 uint2 (8B) per edge;
// 2-stage software pipeline.

__global__ __launch_bounds__(256) void spmm_slice_kernel(
    const int* __restrict__ row_start, const int2* __restrict__ recs,
    const uint2* __restrict__ vq,     // gather plane [N][8] uint2
    const uint2* __restrict__ pq,     // prev plane
    float alpha, float beta,
    uint2* __restrict__ yq) {         // out plane
  int wid = blockIdx.x * 4 + (threadIdx.x >> 6);
  int lane = threadIdx.x & 63;
  int eslot = lane >> 3;  // 0..7
  int lid = lane & 7;     // 0..7
  const int stride = SPMM_BLOCKS * 4;

  for (int row = wid; row < N_NODES; row += stride) {
    int s = row_start[row];
    int e = row_start[row + 1];

    uint2 pv = make_uint2(0u, 0u);
    if (eslot == 0) pv = pq[(size_t)row * 8 + lid];  // hoisted epilogue load

    float acc[4] = {0.f, 0.f, 0.f, 0.f};

    int idx = s + eslot;
    int2 rec0 = (idx < e) ? recs[idx] : make_int2(0, 0);  // val bits 0 -> 0.0f
    uint2 g0 = vq[(size_t)rec0.x * 8 + lid];

    int base = s;
    for (; base + 8 < e; base += 8) {
      int nidx = base + 8 + eslot;
      int2 rec1 = (nidx < e) ? recs[nidx] : make_int2(0, 0);
      uint2 g1 = vq[(size_t)rec1.x * 8 + lid];

      float val = __int_as_float(rec0.y);
      acc[0] += val * bflo(g0.x);
      acc[1] += val * bfhi(g0.x);
      acc[2] += val * bflo(g0.y);
      acc[3] += val * bfhi(g0.y);

      rec0 = rec1;
      g0 = g1;
    }
    {
      float val = __int_as_float(rec0.y);
      acc[0] += val * bflo(g0.x);
      acc[1] += val * bfhi(g0.x);
      acc[2] += val * bflo(g0.y);
      acc[3] += val * bfhi(g0.y);
    }

#pragma unroll
    for (int i = 0; i < 4; ++i) {
      acc[i] += __shfl_xor(acc[i], 8);
      acc[i] += __shfl_xor(acc[i], 16);
      acc[i] += __shfl_xor(acc[i], 32);
    }

    if (eslot == 0) {
      float r0 = alpha * acc[0] + beta * bflo(pv.x);
      float r1 = alpha * acc[1] + beta * bfhi(pv.x);
      float r2 = alpha * acc[2] + beta * bflo(pv.y);
      float r3 = alpha * acc[3] + beta * bfhi(pv.y);
      uint2 o;
      o.x = (unsigned)(unsigned short)f2bf(r0) | ((unsigned)(unsigned short)f2bf(r1) << 16);
      o.y = (unsigned)(unsigned short)f2bf(r2) | ((unsigned)(unsigned short)f2bf(r3) << 16);
      yq[(size_t)row * 8 + lid] = o;
    }
  }
}

// ---------------- MFMA GEMM: out[n][o] = bias[o] + sum_K A[n][K] * Wb[o][K] ----
// A matrices are slice-major (3 planes of [N_PAD][32]). K = seg*96 + t*32 + j.

__global__ __launch_bounds__(256) void gemm_mfma_kernel(
    const short* __restrict__ s0, const short* __restrict__ s1,
    const short* __restrict__ s2, const short* __restrict__ s3,
    const short* __restrict__ Bm,  // [128][384] bf16, k-major K
    const float* __restrict__ bias,
    float* __restrict__ out) {
  int tid = threadIdx.x;
  int wave = tid >> 6;
  int lane = tid & 63;
  int n0 = blockIdx.x * 64;
  int o0 = wave * 32;
  int lr = lane & 15;        // row-in-A-frag / col-in-B-frag
  int lk = (lane >> 4) * 8;  // k offset within frag

  f32x4 acc[4][2];
#pragma unroll
  for (int m = 0; m < 4; ++m)
#pragma unroll
    for (int nn = 0; nn < 2; ++nn) acc[m][nn] = (f32x4){0.f, 0.f, 0.f, 0.f};

  const short* segs[4] = {s0, s1, s2, s3};
  const short* bptr = Bm + (size_t)(o0 + lr) * KTOT + lk;

#pragma unroll
  for (int seg = 0; seg < 4; ++seg) {
#pragma unroll
    for (int t = 0; t < 3; ++t) {
      int kt = seg * 3 + t;
      const short* aseg = segs[seg] + (size_t)t * PSTR + (size_t)(n0 + lr) * 32 + lk;
      bf16x8 a[4], b[2];
#pragma unroll
      for (int m = 0; m < 4; ++m)
        a[m] = *reinterpret_cast<const bf16x8*>(aseg + (size_t)m * 16 * 32);
#pragma unroll
      for (int nn = 0; nn < 2; ++nn)
        b[nn] = *reinterpret_cast<const bf16x8*>(bptr + (size_t)nn * 16 * KTOT + kt * 32);
#pragma unroll
      for (int m = 0; m < 4; ++m)
#pragma unroll
        for (int nn = 0; nn < 2; ++nn)
          acc[m][nn] = __builtin_amdgcn_mfma_f32_16x16x32_bf16(a[m], b[nn], acc[m][nn], 0, 0, 0);
    }
  }

  int orow = (lane >> 4) * 4;  // C/D: col = lane&15, row = (lane>>4)*4 + reg
#pragma unroll
  for (int m = 0; m < 4; ++m) {
#pragma unroll
    for (int nn = 0; nn < 2; ++nn) {
      int oc = o0 + nn * 16 + lr;
      float bv = bias[oc];
#pragma unroll
      for (int j = 0; j < 4; ++j) {
        int n = n0 + m * 16 + orow + j;
        if (n < N_NODES) out[(size_t)n * OUT_F + oc] = acc[m][nn][j] + bv;
      }
    }
  }
}

// ---------------- launch ----------------

extern "C" void kernel_launch(void* const* d_in, const int* in_sizes, int n_in,
                              void* d_out, int out_size, void* d_ws, size_t ws_size,
                              hipStream_t stream) {
  const float* x = (const float*)d_in[0];
  const int* lap_rows = (const int*)d_in[1];
  const int* lap_cols = (const int*)d_in[2];
  const float* lap_vals = (const float*)d_in[3];
  const float* W = (const float*)d_in[4];
  const float* b = (const float*)d_in[5];
  float* out = (float*)d_out;

  char* ws = (char*)d_ws;
  short* xb = (short*)ws;            ws += (size_t)N_PAD * IN_F * 2;  // 9.6 MB
  short* T1b = (short*)ws;           ws += (size_t)N_PAD * IN_F * 2;
  short* T2b = (short*)ws;           ws += (size_t)N_PAD * IN_F * 2;
  short* T3b = (short*)ws;           ws += (size_t)N_PAD * IN_F * 2;
  short* Wb = (short*)ws;            ws += (size_t)OUT_F * KTOT * 2;  // 96 KB
  int* hist = (int*)ws;              ws += (size_t)NB * NBLK * 4;     // 613 KB
  int* off = (int*)ws;               ws += (size_t)NB * NBLK * 4;
  int* total = (int*)ws;             ws += (size_t)NB * 4;
  int* bucket_start = (int*)ws;      ws += (size_t)(NB + 2) * 4;
  int* row_start = (int*)ws;         ws += (size_t)(N_NODES + 8) * 4;
  ws = (char*)(((size_t)ws + 15) & ~(size_t)15);
  int2* recs = (int2*)ws;            ws += (size_t)N_EDGES * 8;       // 6.4 MB
  int2* recs2 = (int2*)ws;           ws += (size_t)N_EDGES * 8;       // 6.4 MB

  passA_kernel<<<NBLK, 256, 0, stream>>>(lap_rows, hist);
  scanA_kernel<<<NB, 256, 0, stream>>>(hist, off, total);
  scanB_kernel<<<1, 1024, 0, stream>>>(total, bucket_start);
  passB_kernel<<<NBLK, 256, 0, stream>>>(lap_rows, lap_cols, lap_vals, off, bucket_start,
                                         recs);
  bsort_kernel<<<NB, 256, 0, stream>>>(bucket_start, recs, recs2, row_start);

  convert_xw_kernel<<<(NXD + OUT_F * KTOT + 255) / 256, 256, 0, stream>>>(x, (unsigned*)xb,
                                                                          W, Wb);

  uint2* xq = (uint2*)xb;
  uint2* t1q = (uint2*)T1b;
  uint2* t2q = (uint2*)T2b;
  uint2* t3q = (uint2*)T3b;
  for (int s = 0; s < 3; ++s) {
    spmm_slice_kernel<<<SPMM_BLOCKS, 256, 0, stream>>>(row_start, recs2, xq + s * PQ,
                                                       xq + s * PQ, 1.f, 0.f, t1q + s * PQ);
    spmm_slice_kernel<<<SPMM_BLOCKS, 256, 0, stream>>>(row_start, recs2, t1q + s * PQ,
                                                       xq + s * PQ, 2.f, -1.f, t2q + s * PQ);
    spmm_slice_kernel<<<SPMM_BLOCKS, 256, 0, stream>>>(row_start, recs2, t2q + s * PQ,
                                                       t1q + s * PQ, 2.f, -1.f, t3q + s * PQ);
  }

  gemm_mfma_kernel<<<N_PAD / 64, 256, 0, stream>>>(xb, T1b, T2b, T3b, Wb, b, out);
}